// Round 13
// baseline (344.946 us; speedup 1.0000x reference)
//
#include <hip/hip_runtime.h>
#include <hip/hip_bf16.h>
#include <hip/hip_fp16.h>
#include <hip/hip_cooperative_groups.h>

#define N_NODES 50000
#define HEADS 8
#define CHANS 10
#define HC 80
#define PADH 12               // halfs per head chunk in padded rows (24 B)
#define PHL 96                // padded row stride in halfs (192 B)
#define F_IN 128
#define E_EDGES 1600000
#define E_TOT (E_EDGES + N_NODES)
#define NEG_SLOPE 0.2f
#define NBUCK 3125            // 50000 / 16 (16 nodes per bucket)
#define NCHUNK 128
#define CHUNK ((E_TOT + NCHUNK - 1) / NCHUNK)
#define GEMM_TILES ((N_NODES + 127) / 128)
#define XS_STRIDE 40          // LDS stride pads (halfs) -> 2-way max bank alias
#define WS_STRIDE 40

typedef _Float16 f16x8 __attribute__((ext_vector_type(8)));
typedef float f32x4 __attribute__((ext_vector_type(4)));

#if __has_builtin(__builtin_amdgcn_fdot2) && __has_builtin(__builtin_elementwise_max)
#define USE_PK_SCORE 1
typedef _Float16 h2 __attribute__((ext_vector_type(2)));
#else
#define USE_PK_SCORE 0
#endif

__device__ inline void load_edge(const void* ei, int is64, int e, int& src, int& dst) {
    if (e < E_EDGES) {
        if (is64) {
            src = ((const int*)ei)[2 * e];            // little-endian low word
            dst = ((const int*)ei)[2 * (E_EDGES + e)];
        } else {
            src = ((const int*)ei)[e];
            dst = ((const int*)ei)[E_EDGES + e];
        }
    } else {
        src = dst = e - E_EDGES;
    }
}

__device__ inline int load_dst(const void* ei, int is64, int e) {
    if (e < E_EDGES) {
        if (is64) return ((const int*)ei)[2 * (E_EDGES + e)];
        return ((const int*)ei)[E_EDGES + e];
    }
    return e - E_EDGES;
}

__device__ inline int detect_is64(const void* ei, int tid, int* s_flag) {
    if (tid < 64) {
        const int* p = (const int*)ei;
        bool ok = (p[2 * tid + 1] == 0) && (p[2 * (tid + 64) + 1] == 0);
        unsigned long long m = __ballot(ok);
        if (tid == 0) *s_flag = (m == ~0ull) ? 1 : 0;
    }
    return 0;
}

// ---------------------------------------------------------------------------
// Phase 1 (fused): blocks [0,NCHUNK) = per-chunk bucket histogram with global
// range reservation; blocks [NCHUNK, NCHUNK+480) = weight fp16 preconvert.
__global__ __launch_bounds__(256) void hist_wconv_kernel(
        const void* ei, int* __restrict__ hist, int* __restrict__ bcount,
        const float* __restrict__ Wl0, const float* __restrict__ Wr0,
        const float* __restrict__ Wl1, const float* __restrict__ Wr1,
        const float* __restrict__ Wl2, const float* __restrict__ Wr2,
        __half* __restrict__ wt) {
    int blk = blockIdx.x;
    int tid = threadIdx.x;
    if (blk >= NCHUNK) {
        if (tid < 128) {
            int g = blk - NCHUNK;
            int layer = g / 160, c = g - layer * 160;
            int kp = tid;
            const float* Wl = (layer == 0) ? Wl0 : (layer == 1) ? Wl1 : Wl2;
            const float* Wr = (layer == 0) ? Wr0 : (layer == 1) ? Wr1 : Wr2;
            const float* W = (c < 80) ? Wl : Wr;
            int cc = (c < 80) ? c : c - 80;
            float v = 0.f;
            if (layer == 0) {
                if (kp < F_IN) v = W[kp * 80 + cc];
            } else {
                int hh = kp / PADH, c2 = kp - hh * PADH;
                if (kp < PHL && c2 < CHANS)
                    v = W[(hh * CHANS + c2) * 80 + cc];
            }
            wt[(size_t)g * 128 + kp] = __float2half_rn(v);
        }
        return;
    }
    __shared__ int h[NBUCK];
    __shared__ int s_is64;
    for (int i = tid; i < NBUCK; i += 256) h[i] = 0;
    detect_is64(ei, tid, &s_is64);
    __syncthreads();
    int is64 = s_is64;
    int e0 = blk * CHUNK, e1 = min(e0 + CHUNK, E_TOT);
    for (int e = e0 + tid; e < e1; e += 4 * 256) {
        int d[4]; int cnt = 0;
        #pragma unroll
        for (int u = 0; u < 4; u++) {
            int ee = e + u * 256;
            if (ee < e1) { d[u] = load_dst(ei, is64, ee); cnt = u + 1; }
        }
        #pragma unroll
        for (int u = 0; u < 4; u++)
            if (u < cnt) atomicAdd(&h[d[u] >> 4], 1);
    }
    __syncthreads();
    for (int i = tid; i < NBUCK; i += 256) {
        int v = h[i];
        int old = v ? atomicAdd(&bcount[i], v) : 0;
        hist[blk * NBUCK + i] = old;
    }
}

// ---------------------------------------------------------------------------
// Single-block exclusive scan over bcount[NBUCK] -> bbase
__global__ void scan_total_kernel(const int* __restrict__ total, int* __restrict__ bbase) {
    __shared__ int wsum[16];
    __shared__ int wpre[16];
    __shared__ int carry;
    int tid = threadIdx.x;
    int lane = tid & 63, w = tid >> 6;
    if (tid == 0) carry = 0;
    __syncthreads();
    for (int base = 0; base < NBUCK; base += 1024) {
        int idx = base + tid;
        int v = (idx < NBUCK) ? total[idx] : 0;
        int sv = v;
        #pragma unroll
        for (int off = 1; off < 64; off <<= 1) {
            int t = __shfl_up(sv, off, 64);
            if (lane >= off) sv += t;
        }
        if (lane == 63) wsum[w] = sv;
        __syncthreads();
        if (w == 0) {
            int s = (lane < 16) ? wsum[lane] : 0;
            #pragma unroll
            for (int off = 1; off < 16; off <<= 1) {
                int t = __shfl_up(s, off, 64);
                if (lane >= off) s += t;
            }
            if (lane < 16) wpre[lane] = s;
        }
        __syncthreads();
        int pre = carry + ((w > 0) ? wpre[w - 1] : 0);
        if (idx < NBUCK) bbase[idx] = pre + sv - v;
        __syncthreads();
        if (tid == 0) carry += wpre[15];
        __syncthreads();
    }
}

// ---------------------------------------------------------------------------
// Phase 3: deterministic-placement scatter into 16-node buckets. LDS cursors only.
__global__ __launch_bounds__(256) void scatter_sort_kernel(
        const void* ei, const int* __restrict__ hist, const int* __restrict__ bbase,
        int* __restrict__ tmp) {
    __shared__ int cur[NBUCK];
    __shared__ int s_is64;
    int tid = threadIdx.x;
    int blk = blockIdx.x;
    for (int i = tid; i < NBUCK; i += 256)
        cur[i] = bbase[i] + hist[blk * NBUCK + i];
    detect_is64(ei, tid, &s_is64);
    __syncthreads();
    int is64 = s_is64;
    int e0 = blk * CHUNK, e1 = min(e0 + CHUNK, E_TOT);
    for (int e = e0 + tid; e < e1; e += 4 * 256) {
        int s[4], d[4]; int cnt = 0;
        #pragma unroll
        for (int u = 0; u < 4; u++) {
            int ee = e + u * 256;
            if (ee < e1) { load_edge(ei, is64, ee, s[u], d[u]); cnt = u + 1; }
        }
        #pragma unroll
        for (int u = 0; u < 4; u++) {
            if (u < cnt) {
                int pos = atomicAdd(&cur[d[u] >> 4], 1);
                tmp[pos] = (s[u] << 4) | (d[u] & 15);
            }
        }
    }
}

// ---------------------------------------------------------------------------
// Phase 4: bucket-grouped tmp -> node-grouped adj + nstart + deg.
__global__ __launch_bounds__(256) void node_sort_kernel(
        const int* __restrict__ tmp, const int* __restrict__ bbase,
        const int* __restrict__ total,
        int* __restrict__ adj, int* __restrict__ nstart, int* __restrict__ deg) {
    __shared__ int h16[16];
    __shared__ int st16[16];
    __shared__ int cur16[16];
    int tid = threadIdx.x;
    int b = blockIdx.x;
    int base = bbase[b];
    int n = total[b];
    if (tid < 16) h16[tid] = 0;
    __syncthreads();
    for (int k = tid; k < n; k += 256)
        atomicAdd(&h16[tmp[base + k] & 15], 1);
    __syncthreads();
    if (tid == 0) {
        int run = 0;
        #pragma unroll
        for (int c = 0; c < 16; c++) { st16[c] = run; cur16[c] = run; run += h16[c]; }
    }
    __syncthreads();
    for (int k = tid; k < n; k += 256) {
        int p = tmp[base + k];
        int pos = atomicAdd(&cur16[p & 15], 1);
        adj[base + pos] = p >> 4;
    }
    if (tid < 16) {
        nstart[b * 16 + tid] = base + st16[tid];
        deg[b * 16 + tid] = h16[tid];
    }
}

// ---------------------------------------------------------------------------
// Degree permutation, DESCENDING (LPT). Per-block LDS pre-reduction (196
// blocks) keeps global atomics uncontended — do NOT fold into node_sort (R11).
__global__ __launch_bounds__(256) void deghist_kernel(
        const int* __restrict__ deg, int* __restrict__ dh) {
    __shared__ int h[256];
    h[threadIdx.x] = 0;
    __syncthreads();
    int i = blockIdx.x * 256 + threadIdx.x;
    if (i < N_NODES) atomicAdd(&h[min(deg[i], 255)], 1);
    __syncthreads();
    if (h[threadIdx.x]) atomicAdd(&dh[threadIdx.x], h[threadIdx.x]);
}

__global__ void degscan_kernel(const int* __restrict__ dh, int* __restrict__ dcur) {
    __shared__ int s[256];
    int tid = threadIdx.x;
    int idx = 255 - tid;              // descending degree order
    int own = dh[idx];
    s[tid] = own;
    __syncthreads();
    for (int off = 1; off < 256; off <<= 1) {
        int t = (tid >= off) ? s[tid - off] : 0;
        __syncthreads();
        s[tid] += t;
        __syncthreads();
    }
    dcur[idx] = s[tid] - own;         // exclusive, deg 255 first
}

__device__ __forceinline__ void degscatter_body(
        int chunk, const int* __restrict__ deg, int* __restrict__ dcur,
        int* __restrict__ perm) {
    __shared__ int h[256];
    __shared__ int res[256];
    __shared__ int lc[256];
    int tid = threadIdx.x;
    h[tid] = 0; lc[tid] = 0;
    __syncthreads();
    int i = chunk * 256 + tid;
    int d = (i < N_NODES) ? min(deg[i], 255) : -1;
    if (d >= 0) atomicAdd(&h[d], 1);
    __syncthreads();
    res[tid] = h[tid] ? atomicAdd(&dcur[tid], h[tid]) : 0;
    __syncthreads();
    if (d >= 0) {
        int off = atomicAdd(&lc[d], 1);
        perm[res[d] + off] = i;
    }
    __syncthreads();   // safe LDS reuse across grid-stride iterations
}

__global__ __launch_bounds__(256) void degscatter_kernel(
        const int* __restrict__ deg, int* __restrict__ dcur, int* __restrict__ perm) {
    degscatter_body(blockIdx.x, deg, dcur, perm);
}

// ---------------------------------------------------------------------------
// MFMA GEMM tile body: tile = 128 nodes x 160 cols, 4 waves, fp32 accum.
// Layouts (m89/m120-verified): A[m=lane&15][k=quad*8+j]; B[n=lane&15][k=quad*8+j];
// D: col=lane&15, row=quad*4+reg.
__device__ __forceinline__ void gemm_tile_body(
        int tile, const void* __restrict__ xin, int in_fp16, int nkt,
        const __half* __restrict__ wt,
        __half* __restrict__ xlh, float* __restrict__ xr) {
    __shared__ __half xs[128 * XS_STRIDE];
    __shared__ __half ws[160 * WS_STRIDE];
    int tid = threadIdx.x;
    int n0 = tile * 128;
    int w = tid >> 6, lane = tid & 63;
    int quad = lane >> 4, r = lane & 15;

    f32x4 acc[2][10];
    #pragma unroll
    for (int nt = 0; nt < 2; nt++)
        #pragma unroll
        for (int t = 0; t < 10; t++) acc[nt][t] = (f32x4){0.f, 0.f, 0.f, 0.f};

    int snode = tid >> 1;
    int sk = (tid & 1) * 16;
    int sg = n0 + snode;

    for (int kt = 0; kt < nkt; kt++) {
        f16x8 xv0 = (f16x8){0, 0, 0, 0, 0, 0, 0, 0}, xv1 = xv0;
        if (sg < N_NODES) {
            if (in_fp16) {
                const uint4* p = (const uint4*)((const __half*)xin + (size_t)sg * PHL + kt * 32 + sk);
                xv0 = __builtin_bit_cast(f16x8, p[0]);
                xv1 = __builtin_bit_cast(f16x8, p[1]);
            } else {
                const float4* p = (const float4*)((const float*)xin + (size_t)sg * F_IN + kt * 32 + sk);
                float4 f0 = p[0], f1 = p[1], f2 = p[2], f3 = p[3];
                xv0[0] = (_Float16)f0.x; xv0[1] = (_Float16)f0.y;
                xv0[2] = (_Float16)f0.z; xv0[3] = (_Float16)f0.w;
                xv0[4] = (_Float16)f1.x; xv0[5] = (_Float16)f1.y;
                xv0[6] = (_Float16)f1.z; xv0[7] = (_Float16)f1.w;
                xv1[0] = (_Float16)f2.x; xv1[1] = (_Float16)f2.y;
                xv1[2] = (_Float16)f2.z; xv1[3] = (_Float16)f2.w;
                xv1[4] = (_Float16)f3.x; xv1[5] = (_Float16)f3.y;
                xv1[6] = (_Float16)f3.z; xv1[7] = (_Float16)f3.w;
            }
        }
        __syncthreads();   // protect previous iteration's (or tile's) LDS reads
        *(uint4*)(&xs[snode * XS_STRIDE + sk]) = __builtin_bit_cast(uint4, xv0);
        *(uint4*)(&xs[snode * XS_STRIDE + sk + 8]) = __builtin_bit_cast(uint4, xv1);
        for (int u = tid; u < 640; u += 256) {
            int c = u >> 2, k8 = (u & 3) * 8;
            uint4 wv = *(const uint4*)(wt + c * 128 + kt * 32 + k8);
            *(uint4*)(&ws[c * WS_STRIDE + k8]) = wv;
        }
        __syncthreads();
        #pragma unroll
        for (int nt = 0; nt < 2; nt++) {
            f16x8 a = __builtin_bit_cast(f16x8,
                         *(const uint4*)(&xs[(w * 32 + nt * 16 + r) * XS_STRIDE + quad * 8]));
            #pragma unroll
            for (int ct = 0; ct < 10; ct++) {
                f16x8 bf = __builtin_bit_cast(f16x8,
                              *(const uint4*)(&ws[(ct * 16 + r) * WS_STRIDE + quad * 8]));
                acc[nt][ct] = __builtin_amdgcn_mfma_f32_16x16x32_f16(a, bf, acc[nt][ct], 0, 0, 0);
            }
        }
    }
    __syncthreads();   // drain LDS reads before next tile overwrites
    #pragma unroll
    for (int nt = 0; nt < 2; nt++) {
        #pragma unroll
        for (int ct = 0; ct < 10; ct++) {
            int col = ct * 16 + r;
            #pragma unroll
            for (int reg = 0; reg < 4; reg++) {
                int node = n0 + w * 32 + nt * 16 + quad * 4 + reg;
                if (node < N_NODES) {
                    float v = acc[nt][ct][reg];
                    if (col < 80) {
                        int hh = col / 10, cc = col - hh * 10;
                        xlh[(size_t)node * PHL + hh * PADH + cc] = __float2half_rn(v);
                    } else {
                        xr[(size_t)node * HC + (col - 80)] = v;
                    }
                }
            }
        }
    }
}

__global__ __launch_bounds__(256) void gemm_mfma_kernel(
        const void* __restrict__ xin, int in_fp16, int nkt,
        const __half* __restrict__ wt,
        __half* __restrict__ xlh, float* __restrict__ xr) {
    gemm_tile_body(blockIdx.x, xin, in_fp16, nkt, wt, xlh, xr);
}

// ---------------------------------------------------------------------------
__device__ inline void cvt10(uint2 a, uint2 b, uint2 c, float* v) {
    __half2 h;
    h = *(__half2*)&a.x; v[0] = __low2float(h); v[1] = __high2float(h);
    h = *(__half2*)&a.y; v[2] = __low2float(h); v[3] = __high2float(h);
    h = *(__half2*)&b.x; v[4] = __low2float(h); v[5] = __high2float(h);
    h = *(__half2*)&b.y; v[6] = __low2float(h); v[7] = __high2float(h);
    h = *(__half2*)&c.x; v[8] = __low2float(h); v[9] = __high2float(h);
}

// Online-softmax aggregation body. Bucket = 16 nodes (LPT order) x 8 heads x 2
// contiguous splits. fp16 xl rows, batch-8 + batch-4 gathers, packed score.
__device__ __forceinline__ void agg_body(
        int b, const __half* __restrict__ xlh, const float* __restrict__ xr,
        const float* __restrict__ att, const float* __restrict__ bias,
        const int* __restrict__ nstart, const int* __restrict__ deg,
        const int* __restrict__ adj, const int* __restrict__ perm,
        __half* __restrict__ ybuf, float* __restrict__ yout) {
    int tid = threadIdx.x;
    int h = tid & 7;
    int split = (tid >> 3) & 1;
    int i_local = tid >> 4;
    int node = perm[b * 16 + i_local];

    int s0 = nstart[node];
    int dg = deg[node];
    int cnt0 = (dg + 1) >> 1;
    int cnt = split ? (dg - cnt0) : cnt0;
    int k0 = s0 + split * cnt0;

#if USE_PK_SCORE
    h2 xrh[5], atth[5];
    #pragma unroll
    for (int p = 0; p < 5; p++) {
        xrh[p] = (h2){(_Float16)xr[(size_t)node * HC + h * CHANS + 2 * p],
                      (_Float16)xr[(size_t)node * HC + h * CHANS + 2 * p + 1]};
        atth[p] = (h2){(_Float16)att[h * CHANS + 2 * p],
                       (_Float16)att[h * CHANS + 2 * p + 1]};
    }
    const h2 k02 = {(_Float16)NEG_SLOPE, (_Float16)NEG_SLOPE};
    auto score_pk = [&](uint2 a, uint2 bq, uint2 cq) {
        unsigned int wv[5] = {a.x, a.y, bq.x, bq.y, cq.x};
        float s = 0.f;
        #pragma unroll
        for (int p = 0; p < 5; p++) {
            h2 v = __builtin_bit_cast(h2, wv[p]);
            h2 t = v + xrh[p];
            h2 tl = __builtin_elementwise_max(t, t * k02);
            s = __builtin_amdgcn_fdot2(tl, atth[p], s, false);
        }
        return s;
    };
#else
    float xr_c[CHANS], att_c[CHANS];
    #pragma unroll
    for (int c = 0; c < CHANS; c++) {
        xr_c[c]  = xr[(size_t)node * HC + h * CHANS + c];
        att_c[c] = att[h * CHANS + c];
    }
    auto score_pk = [&](uint2 a, uint2 bq, uint2 cq) {
        float v[CHANS];
        cvt10(a, bq, cq, v);
        float s = 0.f;
        #pragma unroll
        for (int c = 0; c < CHANS; c++) {
            float t = v[c] + xr_c[c];
            t = (t > 0.f) ? t : NEG_SLOPE * t;
            s += att_c[c] * t;
        }
        return s;
    };
#endif

    float m = -1e30f, l = 0.f;
    float acc[CHANS];
    #pragma unroll
    for (int c = 0; c < CHANS; c++) acc[c] = 0.f;

    int kk = 0;
    for (; kk + 8 <= cnt; kk += 8) {
        uint2 ra[8], rb[8], rc[8];
        #pragma unroll
        for (int r = 0; r < 8; r++) {
            int j = adj[k0 + kk + r];
            const uint2* p = (const uint2*)(xlh + (size_t)j * PHL + h * PADH);
            ra[r] = p[0]; rb[r] = p[1]; rc[r] = p[2];
        }
        float sc[8];
        #pragma unroll
        for (int r = 0; r < 8; r++) sc[r] = score_pk(ra[r], rb[r], rc[r]);
        float mb = m;
        #pragma unroll
        for (int r = 0; r < 8; r++) mb = fmaxf(mb, sc[r]);
        float scale = __expf(m - mb);
        float ps = 0.f;
        #pragma unroll
        for (int r = 0; r < 8; r++) { sc[r] = __expf(sc[r] - mb); ps += sc[r]; }
        l = l * scale + ps;
        #pragma unroll
        for (int c = 0; c < CHANS; c++) acc[c] *= scale;
        #pragma unroll
        for (int r = 0; r < 8; r++) {
            float v[CHANS];
            cvt10(ra[r], rb[r], rc[r], v);
            #pragma unroll
            for (int c = 0; c < CHANS; c++) acc[c] += sc[r] * v[c];
        }
        m = mb;
    }
    for (; kk + 4 <= cnt; kk += 4) {
        uint2 ra[4], rb[4], rc[4];
        #pragma unroll
        for (int r = 0; r < 4; r++) {
            int j = adj[k0 + kk + r];
            const uint2* p = (const uint2*)(xlh + (size_t)j * PHL + h * PADH);
            ra[r] = p[0]; rb[r] = p[1]; rc[r] = p[2];
        }
        float sc[4];
        #pragma unroll
        for (int r = 0; r < 4; r++) sc[r] = score_pk(ra[r], rb[r], rc[r]);
        float mb = m;
        #pragma unroll
        for (int r = 0; r < 4; r++) mb = fmaxf(mb, sc[r]);
        float scale = __expf(m - mb);
        float ps = 0.f;
        #pragma unroll
        for (int r = 0; r < 4; r++) { sc[r] = __expf(sc[r] - mb); ps += sc[r]; }
        l = l * scale + ps;
        #pragma unroll
        for (int c = 0; c < CHANS; c++) acc[c] *= scale;
        #pragma unroll
        for (int r = 0; r < 4; r++) {
            float v[CHANS];
            cvt10(ra[r], rb[r], rc[r], v);
            #pragma unroll
            for (int c = 0; c < CHANS; c++) acc[c] += sc[r] * v[c];
        }
        m = mb;
    }
    for (; kk < cnt; kk++) {
        int j = adj[k0 + kk];
        const uint2* p = (const uint2*)(xlh + (size_t)j * PHL + h * PADH);
        uint2 a = p[0], bq = p[1], cq = p[2];
        float s = score_pk(a, bq, cq);
        float v[CHANS];
        cvt10(a, bq, cq, v);
        float mn = fmaxf(m, s);
        float scale = __expf(m - mn);
        float pp = __expf(s - mn);
        l = l * scale + pp;
        #pragma unroll
        for (int c = 0; c < CHANS; c++) acc[c] = acc[c] * scale + pp * v[c];
        m = mn;
    }

    // merge the two splits (partner 8 lanes away, same wave)
    {
        float m2 = __shfl_xor(m, 8, 64);
        float l2 = __shfl_xor(l, 8, 64);
        float mn = fmaxf(m, m2);
        float sc1 = __expf(m - mn), sc2 = __expf(m2 - mn);
        l = l * sc1 + l2 * sc2;
        #pragma unroll
        for (int c = 0; c < CHANS; c++) {
            float a2 = __shfl_xor(acc[c], 8, 64);
            acc[c] = acc[c] * sc1 + a2 * sc2;
        }
        m = mn;
    }
    if (split == 0) {
        float inv = 1.f / (l + 1e-16f);
        float z[CHANS];
        #pragma unroll
        for (int c = 0; c < CHANS; c++) {
            float t = acc[c] * inv + bias[h * CHANS + c];
            z[c] = (t > 0.f) ? t : (__expf(t) - 1.f);
        }
        if (yout) {
            #pragma unroll
            for (int c = 0; c < CHANS; c++)
                yout[(size_t)node * HC + h * CHANS + c] = z[c];
        } else {
            __half2 h0 = __halves2half2(__float2half_rn(z[0]), __float2half_rn(z[1]));
            __half2 h1 = __halves2half2(__float2half_rn(z[2]), __float2half_rn(z[3]));
            __half2 h2v = __halves2half2(__float2half_rn(z[4]), __float2half_rn(z[5]));
            __half2 h3 = __halves2half2(__float2half_rn(z[6]), __float2half_rn(z[7]));
            __half2 h4 = __halves2half2(__float2half_rn(z[8]), __float2half_rn(z[9]));
            __half2 h5 = __halves2half2(__half(0.f), __half(0.f));  // zero pad
            uint2* dst = (uint2*)(ybuf + (size_t)node * PHL + h * PADH);
            dst[0] = make_uint2(*(unsigned*)&h0, *(unsigned*)&h1);
            dst[1] = make_uint2(*(unsigned*)&h2v, *(unsigned*)&h3);
            dst[2] = make_uint2(*(unsigned*)&h4, *(unsigned*)&h5);
        }
    }
}

__global__ __launch_bounds__(256, 4) void agg_kernel(
        const __half* __restrict__ xlh, const float* __restrict__ xr,
        const float* __restrict__ att, const float* __restrict__ bias,
        const int* __restrict__ nstart, const int* __restrict__ deg,
        const int* __restrict__ adj, const int* __restrict__ perm,
        __half* __restrict__ ybuf, float* __restrict__ yout) {
    agg_body(blockIdx.x, xlh, xr, att, bias, nstart, deg, adj, perm, ybuf, yout);
}

// ---------------------------------------------------------------------------
// Cooperative per-layer kernel: phase A = (layer0: degscatter) + gemm tiles,
// grid.sync(), phase B = agg buckets. One launch replaces 2-3.
__global__ __launch_bounds__(256) void coop_layer_kernel(
        const void* __restrict__ xin, int in_fp16, int nkt,
        const __half* __restrict__ wt,
        __half* __restrict__ xlh, float* __restrict__ xr,
        const float* __restrict__ att, const float* __restrict__ bias,
        const int* __restrict__ nstart, const int* __restrict__ deg,
        const int* __restrict__ adj, int* __restrict__ perm,
        __half* __restrict__ ybuf, float* __restrict__ yout,
        int do_perm, int* __restrict__ dcur) {
    if (do_perm) {
        int nchunks = (N_NODES + 255) >> 8;
        for (int c = blockIdx.x; c < nchunks; c += gridDim.x)
            degscatter_body(c, deg, dcur, perm);
    }
    for (int t = blockIdx.x; t < GEMM_TILES; t += gridDim.x)
        gemm_tile_body(t, xin, in_fp16, nkt, wt, xlh, xr);
    cooperative_groups::this_grid().sync();
    for (int b = blockIdx.x; b < NBUCK; b += gridDim.x)
        agg_body(b, xlh, xr, att, bias, nstart, deg, adj, perm, ybuf, yout);
}

// ---------------------------------------------------------------------------
extern "C" void kernel_launch(void* const* d_in, const int* in_sizes, int n_in,
                              void* d_out, int out_size, void* d_ws, size_t ws_size,
                              hipStream_t stream) {
    const float* x_in = (const float*)d_in[0];
    const void*  ei   = d_in[1];
    const float* Wl[3] = {(const float*)d_in[2], (const float*)d_in[6],  (const float*)d_in[10]};
    const float* Wr[3] = {(const float*)d_in[3], (const float*)d_in[7],  (const float*)d_in[11]};
    const float* At[3] = {(const float*)d_in[4], (const float*)d_in[8],  (const float*)d_in[12]};
    const float* Bi[3] = {(const float*)d_in[5], (const float*)d_in[9],  (const float*)d_in[13]};
    float* out = (float*)d_out;

    char* ws = (char*)d_ws;
    size_t off = 0;
    auto alloc = [&](size_t bytes) {
        void* p = ws + off;
        off += (bytes + 255) & ~(size_t)255;
        return p;
    };
    __half* xlh   = (__half*)alloc((size_t)N_NODES * PHL * sizeof(__half));
    float*  xr    = (float*)alloc((size_t)N_NODES * HC * sizeof(float));
    __half* buf16 = (__half*)alloc((size_t)N_NODES * PHL * sizeof(__half));
    __half* wt    = (__half*)alloc((size_t)3 * 160 * 128 * sizeof(__half));
    int*   tmp    = (int*)alloc((size_t)E_TOT * sizeof(int));
    int*   adj    = (int*)alloc((size_t)E_TOT * sizeof(int));
    int*   hist   = (int*)alloc((size_t)NCHUNK * NBUCK * sizeof(int));
    int*   bcount = (int*)alloc((size_t)NBUCK * sizeof(int));   // adjacent to dh:
    int*   dh     = (int*)alloc(256 * sizeof(int));             // one memset covers both
    int*   bbase  = (int*)alloc((size_t)NBUCK * sizeof(int));
    int*   nstart = (int*)alloc((size_t)N_NODES * sizeof(int));
    int*   deg    = (int*)alloc((size_t)N_NODES * sizeof(int));
    int*   perm   = (int*)alloc((size_t)N_NODES * sizeof(int));
    int*   dcur   = (int*)alloc(256 * sizeof(int));

    // --- build: fused hist+wconv, scan, scatter, node_sort, deghist/scan ---
    hipMemsetAsync(bcount, 0, (size_t)((char*)dh - (char*)bcount) + 1024, stream);
    hist_wconv_kernel<<<NCHUNK + 480, 256, 0, stream>>>(
        ei, hist, bcount, Wl[0], Wr[0], Wl[1], Wr[1], Wl[2], Wr[2], wt);
    scan_total_kernel<<<1, 1024, 0, stream>>>(bcount, bbase);
    scatter_sort_kernel<<<NCHUNK, 256, 0, stream>>>(ei, hist, bbase, tmp);
    node_sort_kernel<<<NBUCK, 256, 0, stream>>>(tmp, bbase, bcount, adj, nstart, deg);
    int nblocks = (N_NODES + 255) / 256;
    deghist_kernel<<<nblocks, 256, 0, stream>>>(deg, dh);
    degscan_kernel<<<1, 256, 0, stream>>>(dh, dcur);

    // --- cooperative grid sizing (co-residency guaranteed by occupancy) ---
    int perCU = 0;
    hipOccupancyMaxActiveBlocksPerMultiprocessor(&perCU,
        (const void*)coop_layer_kernel, 256, 0);
    int nCU = 0;
    hipDeviceGetAttribute(&nCU, hipDeviceAttributeMultiprocessorCount, 0);
    int cgrid = perCU * nCU;
    if (cgrid > 2048) cgrid = 2048;
    bool use_coop = (cgrid >= 64);

    // --- 3 GATv2 layers ---
    const void* cur = (const void*)x_in;
    int in_fp16 = 0;
    bool perm_done = false;
    for (int layer = 0; layer < 3; layer++) {
        int nkt = (layer == 0) ? 4 : 3;   // K = 128 dense or 96 padded
        const __half* wtl = wt + (size_t)layer * 160 * 128;
        const float* att_l = At[layer];
        const float* bias_l = Bi[layer];
        __half* ybuf = (layer == 2) ? nullptr : buf16;
        float*  yout = (layer == 2) ? out : nullptr;
        int do_perm = (layer == 0) ? 1 : 0;

        if (use_coop) {
            void* kargs[] = {(void*)&cur, (void*)&in_fp16, (void*)&nkt, (void*)&wtl,
                             (void*)&xlh, (void*)&xr, (void*)&att_l, (void*)&bias_l,
                             (void*)&nstart, (void*)&deg, (void*)&adj, (void*)&perm,
                             (void*)&ybuf, (void*)&yout, (void*)&do_perm, (void*)&dcur};
            hipError_t e = hipLaunchCooperativeKernel(
                (const void*)coop_layer_kernel, dim3(cgrid), dim3(256), kargs, 0, stream);
            if (e == hipSuccess) {
                if (do_perm) perm_done = true;
                cur = (const void*)buf16;
                in_fp16 = 1;
                continue;
            }
            use_coop = false;   // fall through to split launches
        }
        if (!perm_done) {
            degscatter_kernel<<<nblocks, 256, 0, stream>>>(deg, dcur, perm);
            perm_done = true;
        }
        gemm_mfma_kernel<<<GEMM_TILES, 256, 0, stream>>>(cur, in_fp16, nkt, wtl, xlh, xr);
        agg_kernel<<<NBUCK, 256, 0, stream>>>(xlh, xr, att_l, bias_l,
                                              nstart, deg, adj, perm, ybuf, yout);
        cur = (const void*)buf16;
        in_fp16 = 1;
    }
}

// Round 14
// 343.586 us; speedup vs baseline: 1.0040x; 1.0040x over previous
//
#include <hip/hip_runtime.h>
#include <hip/hip_bf16.h>
#include <hip/hip_fp16.h>

#define N_NODES 50000
#define HEADS 8
#define CHANS 10
#define HC 80
#define PADH 12               // halfs per head chunk in padded rows (24 B)
#define PHL 96                // padded row stride in halfs (192 B)
#define F_IN 128
#define E_EDGES 1600000
#define E_TOT (E_EDGES + N_NODES)
#define NEG_SLOPE 0.2f
#define NBUCK 3125            // 50000 / 16 (16 nodes per bucket)
#define NCHUNK 128
#define CHUNK ((E_TOT + NCHUNK - 1) / NCHUNK)
#define XS_STRIDE 40          // LDS stride pads (halfs) -> 2-way max bank alias
#define WS_STRIDE 40

typedef _Float16 f16x8 __attribute__((ext_vector_type(8)));
typedef float f32x4 __attribute__((ext_vector_type(4)));

#if __has_builtin(__builtin_amdgcn_fdot2) && __has_builtin(__builtin_elementwise_max)
#define USE_PK 1
typedef _Float16 h2 __attribute__((ext_vector_type(2)));
#else
#define USE_PK 0
#endif

__device__ inline void load_edge(const void* ei, int is64, int e, int& src, int& dst) {
    if (e < E_EDGES) {
        if (is64) {
            src = ((const int*)ei)[2 * e];            // little-endian low word
            dst = ((const int*)ei)[2 * (E_EDGES + e)];
        } else {
            src = ((const int*)ei)[e];
            dst = ((const int*)ei)[E_EDGES + e];
        }
    } else {
        src = dst = e - E_EDGES;
    }
}

__device__ inline int load_dst(const void* ei, int is64, int e) {
    if (e < E_EDGES) {
        if (is64) return ((const int*)ei)[2 * (E_EDGES + e)];
        return ((const int*)ei)[E_EDGES + e];
    }
    return e - E_EDGES;
}

__device__ inline int detect_is64(const void* ei, int tid, int* s_flag) {
    if (tid < 64) {
        const int* p = (const int*)ei;
        bool ok = (p[2 * tid + 1] == 0) && (p[2 * (tid + 64) + 1] == 0);
        unsigned long long m = __ballot(ok);
        if (tid == 0) *s_flag = (m == ~0ull) ? 1 : 0;
    }
    return 0;
}

// ---------------------------------------------------------------------------
// Phase 1 (fused): blocks [0,NCHUNK) = per-chunk bucket histogram with global
// range reservation; blocks [NCHUNK, NCHUNK+480) = weight fp16 preconvert.
__global__ __launch_bounds__(256) void hist_wconv_kernel(
        const void* ei, int* __restrict__ hist, int* __restrict__ bcount,
        const float* __restrict__ Wl0, const float* __restrict__ Wr0,
        const float* __restrict__ Wl1, const float* __restrict__ Wr1,
        const float* __restrict__ Wl2, const float* __restrict__ Wr2,
        __half* __restrict__ wt) {
    int blk = blockIdx.x;
    int tid = threadIdx.x;
    if (blk >= NCHUNK) {
        if (tid < 128) {
            int g = blk - NCHUNK;
            int layer = g / 160, c = g - layer * 160;
            int kp = tid;
            const float* Wl = (layer == 0) ? Wl0 : (layer == 1) ? Wl1 : Wl2;
            const float* Wr = (layer == 0) ? Wr0 : (layer == 1) ? Wr1 : Wr2;
            const float* W = (c < 80) ? Wl : Wr;
            int cc = (c < 80) ? c : c - 80;
            float v = 0.f;
            if (layer == 0) {
                if (kp < F_IN) v = W[kp * 80 + cc];
            } else {
                int hh = kp / PADH, c2 = kp - hh * PADH;
                if (kp < PHL && c2 < CHANS)
                    v = W[(hh * CHANS + c2) * 80 + cc];
            }
            wt[(size_t)g * 128 + kp] = __float2half_rn(v);
        }
        return;
    }
    __shared__ int h[NBUCK];
    __shared__ int s_is64;
    for (int i = tid; i < NBUCK; i += 256) h[i] = 0;
    detect_is64(ei, tid, &s_is64);
    __syncthreads();
    int is64 = s_is64;
    int e0 = blk * CHUNK, e1 = min(e0 + CHUNK, E_TOT);
    for (int e = e0 + tid; e < e1; e += 4 * 256) {
        int d[4]; int cnt = 0;
        #pragma unroll
        for (int u = 0; u < 4; u++) {
            int ee = e + u * 256;
            if (ee < e1) { d[u] = load_dst(ei, is64, ee); cnt = u + 1; }
        }
        #pragma unroll
        for (int u = 0; u < 4; u++)
            if (u < cnt) atomicAdd(&h[d[u] >> 4], 1);
    }
    __syncthreads();
    for (int i = tid; i < NBUCK; i += 256) {
        int v = h[i];
        int old = v ? atomicAdd(&bcount[i], v) : 0;
        hist[blk * NBUCK + i] = old;
    }
}

// ---------------------------------------------------------------------------
// Single-block exclusive scan over bcount[NBUCK] -> bbase
__global__ void scan_total_kernel(const int* __restrict__ total, int* __restrict__ bbase) {
    __shared__ int wsum[16];
    __shared__ int wpre[16];
    __shared__ int carry;
    int tid = threadIdx.x;
    int lane = tid & 63, w = tid >> 6;
    if (tid == 0) carry = 0;
    __syncthreads();
    for (int base = 0; base < NBUCK; base += 1024) {
        int idx = base + tid;
        int v = (idx < NBUCK) ? total[idx] : 0;
        int sv = v;
        #pragma unroll
        for (int off = 1; off < 64; off <<= 1) {
            int t = __shfl_up(sv, off, 64);
            if (lane >= off) sv += t;
        }
        if (lane == 63) wsum[w] = sv;
        __syncthreads();
        if (w == 0) {
            int s = (lane < 16) ? wsum[lane] : 0;
            #pragma unroll
            for (int off = 1; off < 16; off <<= 1) {
                int t = __shfl_up(s, off, 64);
                if (lane >= off) s += t;
            }
            if (lane < 16) wpre[lane] = s;
        }
        __syncthreads();
        int pre = carry + ((w > 0) ? wpre[w - 1] : 0);
        if (idx < NBUCK) bbase[idx] = pre + sv - v;
        __syncthreads();
        if (tid == 0) carry += wpre[15];
        __syncthreads();
    }
}

// ---------------------------------------------------------------------------
// Phase 3: deterministic-placement scatter into 16-node buckets. LDS cursors only.
__global__ __launch_bounds__(256) void scatter_sort_kernel(
        const void* ei, const int* __restrict__ hist, const int* __restrict__ bbase,
        int* __restrict__ tmp) {
    __shared__ int cur[NBUCK];
    __shared__ int s_is64;
    int tid = threadIdx.x;
    int blk = blockIdx.x;
    for (int i = tid; i < NBUCK; i += 256)
        cur[i] = bbase[i] + hist[blk * NBUCK + i];
    detect_is64(ei, tid, &s_is64);
    __syncthreads();
    int is64 = s_is64;
    int e0 = blk * CHUNK, e1 = min(e0 + CHUNK, E_TOT);
    for (int e = e0 + tid; e < e1; e += 4 * 256) {
        int s[4], d[4]; int cnt = 0;
        #pragma unroll
        for (int u = 0; u < 4; u++) {
            int ee = e + u * 256;
            if (ee < e1) { load_edge(ei, is64, ee, s[u], d[u]); cnt = u + 1; }
        }
        #pragma unroll
        for (int u = 0; u < 4; u++) {
            if (u < cnt) {
                int pos = atomicAdd(&cur[d[u] >> 4], 1);
                tmp[pos] = (s[u] << 4) | (d[u] & 15);
            }
        }
    }
}

// ---------------------------------------------------------------------------
// Phase 4: bucket-grouped tmp -> node-grouped adj + nstart + deg.
__global__ __launch_bounds__(256) void node_sort_kernel(
        const int* __restrict__ tmp, const int* __restrict__ bbase,
        const int* __restrict__ total,
        int* __restrict__ adj, int* __restrict__ nstart, int* __restrict__ deg) {
    __shared__ int h16[16];
    __shared__ int st16[16];
    __shared__ int cur16[16];
    int tid = threadIdx.x;
    int b = blockIdx.x;
    int base = bbase[b];
    int n = total[b];
    if (tid < 16) h16[tid] = 0;
    __syncthreads();
    for (int k = tid; k < n; k += 256)
        atomicAdd(&h16[tmp[base + k] & 15], 1);
    __syncthreads();
    if (tid == 0) {
        int run = 0;
        #pragma unroll
        for (int c = 0; c < 16; c++) { st16[c] = run; cur16[c] = run; run += h16[c]; }
    }
    __syncthreads();
    for (int k = tid; k < n; k += 256) {
        int p = tmp[base + k];
        int pos = atomicAdd(&cur16[p & 15], 1);
        adj[base + pos] = p >> 4;
    }
    if (tid < 16) {
        nstart[b * 16 + tid] = base + st16[tid];
        deg[b * 16 + tid] = h16[tid];
    }
}

// ---------------------------------------------------------------------------
// Degree permutation, DESCENDING (LPT). Per-block LDS pre-reduction (196
// blocks) keeps global atomics uncontended — do NOT fold into node_sort (R11).
__global__ __launch_bounds__(256) void deghist_kernel(
        const int* __restrict__ deg, int* __restrict__ dh) {
    __shared__ int h[256];
    h[threadIdx.x] = 0;
    __syncthreads();
    int i = blockIdx.x * 256 + threadIdx.x;
    if (i < N_NODES) atomicAdd(&h[min(deg[i], 255)], 1);
    __syncthreads();
    if (h[threadIdx.x]) atomicAdd(&dh[threadIdx.x], h[threadIdx.x]);
}

__global__ void degscan_kernel(const int* __restrict__ dh, int* __restrict__ dcur) {
    __shared__ int s[256];
    int tid = threadIdx.x;
    int idx = 255 - tid;              // descending degree order
    int own = dh[idx];
    s[tid] = own;
    __syncthreads();
    for (int off = 1; off < 256; off <<= 1) {
        int t = (tid >= off) ? s[tid - off] : 0;
        __syncthreads();
        s[tid] += t;
        __syncthreads();
    }
    dcur[idx] = s[tid] - own;         // exclusive, deg 255 first
}

__global__ __launch_bounds__(256) void degscatter_kernel(
        const int* __restrict__ deg, int* __restrict__ dcur, int* __restrict__ perm) {
    __shared__ int h[256];
    __shared__ int res[256];
    __shared__ int lc[256];
    int tid = threadIdx.x;
    h[tid] = 0; lc[tid] = 0;
    __syncthreads();
    int i = blockIdx.x * 256 + tid;
    int d = (i < N_NODES) ? min(deg[i], 255) : -1;
    if (d >= 0) atomicAdd(&h[d], 1);
    __syncthreads();
    res[tid] = h[tid] ? atomicAdd(&dcur[tid], h[tid]) : 0;
    __syncthreads();
    if (d >= 0) {
        int off = atomicAdd(&lc[d], 1);
        perm[res[d] + off] = i;
    }
}

// ---------------------------------------------------------------------------
// MFMA GEMM: tile 128 nodes x 160 cols, 4 waves, fp32 accum.
// Layouts (m89/m120-verified): A[m=lane&15][k=quad*8+j]; B[n=lane&15][k=quad*8+j];
// D: col=lane&15, row=quad*4+reg.
__global__ __launch_bounds__(256) void gemm_mfma_kernel(
        const void* __restrict__ xin, int in_fp16, int nkt,
        const __half* __restrict__ wt,
        __half* __restrict__ xlh, float* __restrict__ xr) {
    __shared__ __half xs[128 * XS_STRIDE];
    __shared__ __half ws[160 * WS_STRIDE];
    int tid = threadIdx.x;
    int n0 = blockIdx.x * 128;
    int w = tid >> 6, lane = tid & 63;
    int quad = lane >> 4, r = lane & 15;

    f32x4 acc[2][10];
    #pragma unroll
    for (int nt = 0; nt < 2; nt++)
        #pragma unroll
        for (int t = 0; t < 10; t++) acc[nt][t] = (f32x4){0.f, 0.f, 0.f, 0.f};

    int snode = tid >> 1;
    int sk = (tid & 1) * 16;
    int sg = n0 + snode;

    for (int kt = 0; kt < nkt; kt++) {
        f16x8 xv0 = (f16x8){0, 0, 0, 0, 0, 0, 0, 0}, xv1 = xv0;
        if (sg < N_NODES) {
            if (in_fp16) {
                const uint4* p = (const uint4*)((const __half*)xin + (size_t)sg * PHL + kt * 32 + sk);
                xv0 = __builtin_bit_cast(f16x8, p[0]);
                xv1 = __builtin_bit_cast(f16x8, p[1]);
            } else {
                const float4* p = (const float4*)((const float*)xin + (size_t)sg * F_IN + kt * 32 + sk);
                float4 f0 = p[0], f1 = p[1], f2 = p[2], f3 = p[3];
                xv0[0] = (_Float16)f0.x; xv0[1] = (_Float16)f0.y;
                xv0[2] = (_Float16)f0.z; xv0[3] = (_Float16)f0.w;
                xv0[4] = (_Float16)f1.x; xv0[5] = (_Float16)f1.y;
                xv0[6] = (_Float16)f1.z; xv0[7] = (_Float16)f1.w;
                xv1[0] = (_Float16)f2.x; xv1[1] = (_Float16)f2.y;
                xv1[2] = (_Float16)f2.z; xv1[3] = (_Float16)f2.w;
                xv1[4] = (_Float16)f3.x; xv1[5] = (_Float16)f3.y;
                xv1[6] = (_Float16)f3.z; xv1[7] = (_Float16)f3.w;
            }
        }
        __syncthreads();   // protect previous iteration's LDS reads
        *(uint4*)(&xs[snode * XS_STRIDE + sk]) = __builtin_bit_cast(uint4, xv0);
        *(uint4*)(&xs[snode * XS_STRIDE + sk + 8]) = __builtin_bit_cast(uint4, xv1);
        for (int u = tid; u < 640; u += 256) {
            int c = u >> 2, k8 = (u & 3) * 8;
            uint4 wv = *(const uint4*)(wt + c * 128 + kt * 32 + k8);
            *(uint4*)(&ws[c * WS_STRIDE + k8]) = wv;
        }
        __syncthreads();
        #pragma unroll
        for (int nt = 0; nt < 2; nt++) {
            f16x8 a = __builtin_bit_cast(f16x8,
                         *(const uint4*)(&xs[(w * 32 + nt * 16 + r) * XS_STRIDE + quad * 8]));
            #pragma unroll
            for (int ct = 0; ct < 10; ct++) {
                f16x8 bf = __builtin_bit_cast(f16x8,
                              *(const uint4*)(&ws[(ct * 16 + r) * WS_STRIDE + quad * 8]));
                acc[nt][ct] = __builtin_amdgcn_mfma_f32_16x16x32_f16(a, bf, acc[nt][ct], 0, 0, 0);
            }
        }
    }
    #pragma unroll
    for (int nt = 0; nt < 2; nt++) {
        #pragma unroll
        for (int ct = 0; ct < 10; ct++) {
            int col = ct * 16 + r;
            #pragma unroll
            for (int reg = 0; reg < 4; reg++) {
                int node = n0 + w * 32 + nt * 16 + quad * 4 + reg;
                if (node < N_NODES) {
                    float v = acc[nt][ct][reg];
                    if (col < 80) {
                        int hh = col / 10, cc = col - hh * 10;
                        xlh[(size_t)node * PHL + hh * PADH + cc] = __float2half_rn(v);
                    } else {
                        xr[(size_t)node * HC + (col - 80)] = v;
                    }
                }
            }
        }
    }
}

// ---------------------------------------------------------------------------
__device__ inline void cvt10(uint2 a, uint2 b, uint2 c, float* v) {
    __half2 h;
    h = *(__half2*)&a.x; v[0] = __low2float(h); v[1] = __high2float(h);
    h = *(__half2*)&a.y; v[2] = __low2float(h); v[3] = __high2float(h);
    h = *(__half2*)&b.x; v[4] = __low2float(h); v[5] = __high2float(h);
    h = *(__half2*)&b.y; v[6] = __low2float(h); v[7] = __high2float(h);
    h = *(__half2*)&c.x; v[8] = __low2float(h); v[9] = __high2float(h);
}

// Online-softmax aggregation. Block = 16 nodes (LPT order) x 8 heads x 2
// contiguous splits; batch-8 + batch-4 gathers; packed-fp16 score AND
// packed-fp16 accumulator (no per-row cvt; 5 pk_fma per row).
__global__ __launch_bounds__(256, 4) void agg_kernel(
        const __half* __restrict__ xlh, const float* __restrict__ xr,
        const float* __restrict__ att, const float* __restrict__ bias,
        const int* __restrict__ nstart, const int* __restrict__ deg,
        const int* __restrict__ adj, const int* __restrict__ perm,
        __half* __restrict__ ybuf, float* __restrict__ yout) {
    int tid = threadIdx.x;
    int b = blockIdx.x;
    int h = tid & 7;
    int split = (tid >> 3) & 1;
    int i_local = tid >> 4;
    int node = perm[b * 16 + i_local];

    int s0 = nstart[node];
    int dg = deg[node];
    int cnt0 = (dg + 1) >> 1;
    int cnt = split ? (dg - cnt0) : cnt0;
    int k0 = s0 + split * cnt0;

#if USE_PK
    h2 xrh[5], atth[5];
    #pragma unroll
    for (int p = 0; p < 5; p++) {
        xrh[p] = (h2){(_Float16)xr[(size_t)node * HC + h * CHANS + 2 * p],
                      (_Float16)xr[(size_t)node * HC + h * CHANS + 2 * p + 1]};
        atth[p] = (h2){(_Float16)att[h * CHANS + 2 * p],
                       (_Float16)att[h * CHANS + 2 * p + 1]};
    }
    const h2 k02 = {(_Float16)NEG_SLOPE, (_Float16)NEG_SLOPE};
    auto score_pk = [&](const unsigned int* wv) {
        float s = 0.f;
        #pragma unroll
        for (int p = 0; p < 5; p++) {
            h2 v = __builtin_bit_cast(h2, wv[p]);
            h2 t = v + xrh[p];
            h2 tl = __builtin_elementwise_max(t, t * k02);
            s = __builtin_amdgcn_fdot2(tl, atth[p], s, false);
        }
        return s;
    };

    float m = -1e30f, l = 0.f;
    h2 acc[5];
    #pragma unroll
    for (int p = 0; p < 5; p++) acc[p] = (h2){(_Float16)0.f, (_Float16)0.f};

    int kk = 0;
    for (; kk + 8 <= cnt; kk += 8) {
        unsigned int w[8][5];
        #pragma unroll
        for (int r = 0; r < 8; r++) {
            int j = adj[k0 + kk + r];
            const uint2* p = (const uint2*)(xlh + (size_t)j * PHL + h * PADH);
            uint2 a = p[0], bq = p[1], cq = p[2];
            w[r][0] = a.x; w[r][1] = a.y; w[r][2] = bq.x; w[r][3] = bq.y; w[r][4] = cq.x;
        }
        float sc[8];
        #pragma unroll
        for (int r = 0; r < 8; r++) sc[r] = score_pk(w[r]);
        float mb = m;
        #pragma unroll
        for (int r = 0; r < 8; r++) mb = fmaxf(mb, sc[r]);
        float scale = __expf(m - mb);
        float ps = 0.f;
        #pragma unroll
        for (int r = 0; r < 8; r++) { sc[r] = __expf(sc[r] - mb); ps += sc[r]; }
        l = l * scale + ps;
        _Float16 sch = (_Float16)scale;
        h2 sch2 = (h2){sch, sch};
        #pragma unroll
        for (int p = 0; p < 5; p++) acc[p] *= sch2;
        #pragma unroll
        for (int r = 0; r < 8; r++) {
            _Float16 pr = (_Float16)sc[r];
            h2 pr2 = (h2){pr, pr};
            #pragma unroll
            for (int p = 0; p < 5; p++)
                acc[p] += pr2 * __builtin_bit_cast(h2, w[r][p]);
        }
        m = mb;
    }
    for (; kk + 4 <= cnt; kk += 4) {
        unsigned int w[4][5];
        #pragma unroll
        for (int r = 0; r < 4; r++) {
            int j = adj[k0 + kk + r];
            const uint2* p = (const uint2*)(xlh + (size_t)j * PHL + h * PADH);
            uint2 a = p[0], bq = p[1], cq = p[2];
            w[r][0] = a.x; w[r][1] = a.y; w[r][2] = bq.x; w[r][3] = bq.y; w[r][4] = cq.x;
        }
        float sc[4];
        #pragma unroll
        for (int r = 0; r < 4; r++) sc[r] = score_pk(w[r]);
        float mb = m;
        #pragma unroll
        for (int r = 0; r < 4; r++) mb = fmaxf(mb, sc[r]);
        float scale = __expf(m - mb);
        float ps = 0.f;
        #pragma unroll
        for (int r = 0; r < 4; r++) { sc[r] = __expf(sc[r] - mb); ps += sc[r]; }
        l = l * scale + ps;
        _Float16 sch = (_Float16)scale;
        h2 sch2 = (h2){sch, sch};
        #pragma unroll
        for (int p = 0; p < 5; p++) acc[p] *= sch2;
        #pragma unroll
        for (int r = 0; r < 4; r++) {
            _Float16 pr = (_Float16)sc[r];
            h2 pr2 = (h2){pr, pr};
            #pragma unroll
            for (int p = 0; p < 5; p++)
                acc[p] += pr2 * __builtin_bit_cast(h2, w[r][p]);
        }
        m = mb;
    }
    for (; kk < cnt; kk++) {
        int j = adj[k0 + kk];
        const uint2* p = (const uint2*)(xlh + (size_t)j * PHL + h * PADH);
        uint2 a = p[0], bq = p[1], cq = p[2];
        unsigned int w[5] = {a.x, a.y, bq.x, bq.y, cq.x};
        float s = score_pk(w);
        float mn = fmaxf(m, s);
        float scale = __expf(m - mn);
        float pp = __expf(s - mn);
        l = l * scale + pp;
        _Float16 sch = (_Float16)scale, prh = (_Float16)pp;
        h2 sch2 = (h2){sch, sch}, pr2 = (h2){prh, prh};
        #pragma unroll
        for (int p5 = 0; p5 < 5; p5++)
            acc[p5] = acc[p5] * sch2 + pr2 * __builtin_bit_cast(h2, w[p5]);
        m = mn;
    }

    // merge the two splits (partner 8 lanes away, same wave)
    float accm[CHANS];
    float lt;
    {
        float m2 = __shfl_xor(m, 8, 64);
        float l2 = __shfl_xor(l, 8, 64);
        float mn = fmaxf(m, m2);
        float sc1 = __expf(m - mn), sc2 = __expf(m2 - mn);
        lt = l * sc1 + l2 * sc2;
        #pragma unroll
        for (int p = 0; p < 5; p++) {
            unsigned int ua = __builtin_bit_cast(unsigned int, acc[p]);
            unsigned int ub = (unsigned int)__shfl_xor((int)ua, 8, 64);
            h2 va = __builtin_bit_cast(h2, ua);
            h2 vb = __builtin_bit_cast(h2, ub);
            accm[2 * p]     = (float)va[0] * sc1 + (float)vb[0] * sc2;
            accm[2 * p + 1] = (float)va[1] * sc1 + (float)vb[1] * sc2;
        }
    }
#else
    float xr_c[CHANS], att_c[CHANS];
    #pragma unroll
    for (int c = 0; c < CHANS; c++) {
        xr_c[c]  = xr[(size_t)node * HC + h * CHANS + c];
        att_c[c] = att[h * CHANS + c];
    }
    float m = -1e30f, l = 0.f;
    float acc[CHANS];
    #pragma unroll
    for (int c = 0; c < CHANS; c++) acc[c] = 0.f;
    for (int kk = 0; kk < cnt; kk++) {
        int j = adj[k0 + kk];
        const uint2* p = (const uint2*)(xlh + (size_t)j * PHL + h * PADH);
        uint2 a = p[0], bq = p[1], cq = p[2];
        float v[CHANS];
        cvt10(a, bq, cq, v);
        float s = 0.f;
        #pragma unroll
        for (int c = 0; c < CHANS; c++) {
            float t = v[c] + xr_c[c];
            t = (t > 0.f) ? t : NEG_SLOPE * t;
            s += att_c[c] * t;
        }
        float mn = fmaxf(m, s);
        float scale = __expf(m - mn);
        float pp = __expf(s - mn);
        l = l * scale + pp;
        #pragma unroll
        for (int c = 0; c < CHANS; c++) acc[c] = acc[c] * scale + pp * v[c];
        m = mn;
    }
    float accm[CHANS];
    float lt;
    {
        float m2 = __shfl_xor(m, 8, 64);
        float l2 = __shfl_xor(l, 8, 64);
        float mn = fmaxf(m, m2);
        float sc1 = __expf(m - mn), sc2 = __expf(m2 - mn);
        lt = l * sc1 + l2 * sc2;
        #pragma unroll
        for (int c = 0; c < CHANS; c++) {
            float a2 = __shfl_xor(acc[c], 8, 64);
            accm[c] = acc[c] * sc1 + a2 * sc2;
        }
    }
#endif

    if (split == 0) {
        float inv = 1.f / (lt + 1e-16f);
        float z[CHANS];
        #pragma unroll
        for (int c = 0; c < CHANS; c++) {
            float t = accm[c] * inv + bias[h * CHANS + c];
            z[c] = (t > 0.f) ? t : (__expf(t) - 1.f);
        }
        if (yout) {
            #pragma unroll
            for (int c = 0; c < CHANS; c++)
                yout[(size_t)node * HC + h * CHANS + c] = z[c];
        } else {
            __half2 h0 = __halves2half2(__float2half_rn(z[0]), __float2half_rn(z[1]));
            __half2 h1 = __halves2half2(__float2half_rn(z[2]), __float2half_rn(z[3]));
            __half2 h2v = __halves2half2(__float2half_rn(z[4]), __float2half_rn(z[5]));
            __half2 h3 = __halves2half2(__float2half_rn(z[6]), __float2half_rn(z[7]));
            __half2 h4 = __halves2half2(__float2half_rn(z[8]), __float2half_rn(z[9]));
            __half2 h5 = __halves2half2(__half(0.f), __half(0.f));  // zero pad
            uint2* dst = (uint2*)(ybuf + (size_t)node * PHL + h * PADH);
            dst[0] = make_uint2(*(unsigned*)&h0, *(unsigned*)&h1);
            dst[1] = make_uint2(*(unsigned*)&h2v, *(unsigned*)&h3);
            dst[2] = make_uint2(*(unsigned*)&h4, *(unsigned*)&h5);
        }
    }
}

// ---------------------------------------------------------------------------
extern "C" void kernel_launch(void* const* d_in, const int* in_sizes, int n_in,
                              void* d_out, int out_size, void* d_ws, size_t ws_size,
                              hipStream_t stream) {
    const float* x_in = (const float*)d_in[0];
    const void*  ei   = d_in[1];
    const float* Wl[3] = {(const float*)d_in[2], (const float*)d_in[6],  (const float*)d_in[10]};
    const float* Wr[3] = {(const float*)d_in[3], (const float*)d_in[7],  (const float*)d_in[11]};
    const float* At[3] = {(const float*)d_in[4], (const float*)d_in[8],  (const float*)d_in[12]};
    const float* Bi[3] = {(const float*)d_in[5], (const float*)d_in[9],  (const float*)d_in[13]};
    float* out = (float*)d_out;

    char* ws = (char*)d_ws;
    size_t off = 0;
    auto alloc = [&](size_t bytes) {
        void* p = ws + off;
        off += (bytes + 255) & ~(size_t)255;
        return p;
    };
    __half* xlh   = (__half*)alloc((size_t)N_NODES * PHL * sizeof(__half));
    float*  xr    = (float*)alloc((size_t)N_NODES * HC * sizeof(float));
    __half* buf16 = (__half*)alloc((size_t)N_NODES * PHL * sizeof(__half));
    __half* wt    = (__half*)alloc((size_t)3 * 160 * 128 * sizeof(__half));
    int*   tmp    = (int*)alloc((size_t)E_TOT * sizeof(int));
    int*   adj    = (int*)alloc((size_t)E_TOT * sizeof(int));
    int*   hist   = (int*)alloc((size_t)NCHUNK * NBUCK * sizeof(int));
    int*   bcount = (int*)alloc((size_t)NBUCK * sizeof(int));   // adjacent to dh:
    int*   dh     = (int*)alloc(256 * sizeof(int));             // one memset covers both
    int*   bbase  = (int*)alloc((size_t)NBUCK * sizeof(int));
    int*   nstart = (int*)alloc((size_t)N_NODES * sizeof(int));
    int*   deg    = (int*)alloc((size_t)N_NODES * sizeof(int));
    int*   perm   = (int*)alloc((size_t)N_NODES * sizeof(int));
    int*   dcur   = (int*)alloc(256 * sizeof(int));

    // --- build: fused hist+wconv, scan, scatter, node_sort, deg trio ---
    hipMemsetAsync(bcount, 0, (size_t)((char*)dh - (char*)bcount) + 1024, stream);
    hist_wconv_kernel<<<NCHUNK + 480, 256, 0, stream>>>(
        ei, hist, bcount, Wl[0], Wr[0], Wl[1], Wr[1], Wl[2], Wr[2], wt);
    scan_total_kernel<<<1, 1024, 0, stream>>>(bcount, bbase);
    scatter_sort_kernel<<<NCHUNK, 256, 0, stream>>>(ei, hist, bbase, tmp);
    node_sort_kernel<<<NBUCK, 256, 0, stream>>>(tmp, bbase, bcount, adj, nstart, deg);
    int nblocks = (N_NODES + 255) / 256;
    deghist_kernel<<<nblocks, 256, 0, stream>>>(deg, dh);
    degscan_kernel<<<1, 256, 0, stream>>>(dh, dcur);
    degscatter_kernel<<<nblocks, 256, 0, stream>>>(deg, dcur, perm);

    // --- 3 GATv2 layers ---
    int gemm_blocks = (N_NODES + 127) / 128;
    const void* cur = (const void*)x_in;
    int in_fp16 = 0;
    for (int layer = 0; layer < 3; layer++) {
        int nkt = (layer == 0) ? 4 : 3;   // K = 128 dense or 96 padded
        gemm_mfma_kernel<<<gemm_blocks, 256, 0, stream>>>(
            cur, in_fp16, nkt, wt + (size_t)layer * 160 * 128, xlh, xr);
        __half* ybuf = (layer == 2) ? nullptr : buf16;
        float*  yout = (layer == 2) ? out : nullptr;
        agg_kernel<<<NBUCK, 256, 0, stream>>>(xlh, xr, At[layer], Bi[layer],
                                              nstart, deg, adj, perm, ybuf, yout);
        cur = (const void*)buf16;
        in_fp16 = 1;
    }
}

// Round 15
// 320.943 us; speedup vs baseline: 1.0748x; 1.0706x over previous
//
#include <hip/hip_runtime.h>
#include <hip/hip_bf16.h>
#include <hip/hip_fp16.h>

#define N_NODES 50000
#define HEADS 8
#define CHANS 10
#define HC 80
#define PHL 80                // DENSE xl row stride in halfs (160 B)
#define F_IN 128
#define E_EDGES 1600000
#define E_TOT (E_EDGES + N_NODES)
#define NEG_SLOPE 0.2f
#define NBUCK 3125            // 50000 / 16 (16 nodes per bucket)
#define NCHUNK 128
#define CHUNK ((E_TOT + NCHUNK - 1) / NCHUNK)
#define GEMM_TILES ((N_NODES + 127) / 128)
#define XS_STRIDE 40          // LDS stride pads (halfs) -> 2-way max bank alias
#define WS_STRIDE 40

typedef _Float16 f16x8 __attribute__((ext_vector_type(8)));
typedef float f32x4 __attribute__((ext_vector_type(4)));

#if __has_builtin(__builtin_amdgcn_fdot2) && __has_builtin(__builtin_elementwise_max)
#define USE_PK 1
typedef _Float16 h2 __attribute__((ext_vector_type(2)));
#else
#define USE_PK 0
#endif

__device__ inline void load_edge(const void* ei, int is64, int e, int& src, int& dst) {
    if (e < E_EDGES) {
        if (is64) {
            src = ((const int*)ei)[2 * e];            // little-endian low word
            dst = ((const int*)ei)[2 * (E_EDGES + e)];
        } else {
            src = ((const int*)ei)[e];
            dst = ((const int*)ei)[E_EDGES + e];
        }
    } else {
        src = dst = e - E_EDGES;
    }
}

__device__ inline int load_dst(const void* ei, int is64, int e) {
    if (e < E_EDGES) {
        if (is64) return ((const int*)ei)[2 * (E_EDGES + e)];
        return ((const int*)ei)[E_EDGES + e];
    }
    return e - E_EDGES;
}

__device__ inline int detect_is64(const void* ei, int tid, int* s_flag) {
    if (tid < 64) {
        const int* p = (const int*)ei;
        bool ok = (p[2 * tid + 1] == 0) && (p[2 * (tid + 64) + 1] == 0);
        unsigned long long m = __ballot(ok);
        if (tid == 0) *s_flag = (m == ~0ull) ? 1 : 0;
    }
    return 0;
}

// ---------------------------------------------------------------------------
// Weight preconvert (standalone, before hist+gemm0): wt[layer][c][kp] fp16,
// kp = dense input feature, zero-padded to 128. Dense activations make layers
// 1-2 identical in form to layer 0 (no pad remap).
__global__ void wconv_kernel(const float* __restrict__ Wl0, const float* __restrict__ Wr0,
                             const float* __restrict__ Wl1, const float* __restrict__ Wr1,
                             const float* __restrict__ Wl2, const float* __restrict__ Wr2,
                             __half* __restrict__ wt) {
    int g = blockIdx.x;
    int layer = g / 160, c = g - layer * 160;
    int kp = threadIdx.x;
    const float* Wl = (layer == 0) ? Wl0 : (layer == 1) ? Wl1 : Wl2;
    const float* Wr = (layer == 0) ? Wr0 : (layer == 1) ? Wr1 : Wr2;
    const float* W = (c < 80) ? Wl : Wr;
    int cc = (c < 80) ? c : c - 80;
    int din = (layer == 0) ? F_IN : HC;
    float v = (kp < din) ? W[kp * 80 + cc] : 0.f;
    wt[(size_t)g * 128 + kp] = __float2half_rn(v);
}

// ---------------------------------------------------------------------------
// MFMA GEMM tile body: tile = 128 nodes x 160 cols, 4 waves, fp32 accum.
// Layouts (m89/m120-verified): A[m=lane&15][k=quad*8+j]; B[n=lane&15][k=quad*8+j];
// D: col=lane&15, row=quad*4+reg. Dense fp16 rows: K=80, groups >=80 masked
// to zero (weights there are zero too).
__device__ __forceinline__ void gemm_tile_body(
        int tile, const void* __restrict__ xin, int in_fp16, int nkt,
        const __half* __restrict__ wt,
        __half* __restrict__ xlh, float* __restrict__ xr,
        __half* xs, __half* ws) {
    int tid = threadIdx.x;
    int n0 = tile * 128;
    int w = tid >> 6, lane = tid & 63;
    int quad = lane >> 4, r = lane & 15;

    f32x4 acc[2][10];
    #pragma unroll
    for (int nt = 0; nt < 2; nt++)
        #pragma unroll
        for (int t = 0; t < 10; t++) acc[nt][t] = (f32x4){0.f, 0.f, 0.f, 0.f};

    int snode = tid >> 1;           // 0..127
    int sk = (tid & 1) * 16;        // half offset within 32-half k-tile
    int sg = n0 + snode;

    for (int kt = 0; kt < nkt; kt++) {
        f16x8 xv0 = (f16x8){0, 0, 0, 0, 0, 0, 0, 0}, xv1 = xv0;
        if (sg < N_NODES) {
            if (in_fp16) {
                int g0 = kt * 32 + sk;          // first half index of this 16-half load
                const uint4* p = (const uint4*)((const __half*)xin + (size_t)sg * PHL + g0);
                if (g0 < PHL)     xv0 = __builtin_bit_cast(f16x8, p[0]);
                if (g0 + 8 < PHL) xv1 = __builtin_bit_cast(f16x8, p[1]);
            } else {
                const float4* p = (const float4*)((const float*)xin + (size_t)sg * F_IN + kt * 32 + sk);
                float4 f0 = p[0], f1 = p[1], f2 = p[2], f3 = p[3];
                xv0[0] = (_Float16)f0.x; xv0[1] = (_Float16)f0.y;
                xv0[2] = (_Float16)f0.z; xv0[3] = (_Float16)f0.w;
                xv0[4] = (_Float16)f1.x; xv0[5] = (_Float16)f1.y;
                xv0[6] = (_Float16)f1.z; xv0[7] = (_Float16)f1.w;
                xv1[0] = (_Float16)f2.x; xv1[1] = (_Float16)f2.y;
                xv1[2] = (_Float16)f2.z; xv1[3] = (_Float16)f2.w;
                xv1[4] = (_Float16)f3.x; xv1[5] = (_Float16)f3.y;
                xv1[6] = (_Float16)f3.z; xv1[7] = (_Float16)f3.w;
            }
        }
        __syncthreads();   // protect previous iteration's LDS reads
        *(uint4*)(&xs[snode * XS_STRIDE + sk]) = __builtin_bit_cast(uint4, xv0);
        *(uint4*)(&xs[snode * XS_STRIDE + sk + 8]) = __builtin_bit_cast(uint4, xv1);
        for (int u = tid; u < 640; u += 256) {
            int c = u >> 2, k8 = (u & 3) * 8;
            uint4 wv = *(const uint4*)(wt + c * 128 + kt * 32 + k8);
            *(uint4*)(&ws[c * WS_STRIDE + k8]) = wv;
        }
        __syncthreads();
        #pragma unroll
        for (int nt = 0; nt < 2; nt++) {
            f16x8 a = __builtin_bit_cast(f16x8,
                         *(const uint4*)(&xs[(w * 32 + nt * 16 + r) * XS_STRIDE + quad * 8]));
            #pragma unroll
            for (int ct = 0; ct < 10; ct++) {
                f16x8 bf = __builtin_bit_cast(f16x8,
                              *(const uint4*)(&ws[(ct * 16 + r) * WS_STRIDE + quad * 8]));
                acc[nt][ct] = __builtin_amdgcn_mfma_f32_16x16x32_f16(a, bf, acc[nt][ct], 0, 0, 0);
            }
        }
    }
    __syncthreads();   // drain before (potential) next use of the shared buffer
    #pragma unroll
    for (int nt = 0; nt < 2; nt++) {
        #pragma unroll
        for (int ct = 0; ct < 10; ct++) {
            int col = ct * 16 + r;
            #pragma unroll
            for (int reg = 0; reg < 4; reg++) {
                int node = n0 + w * 32 + nt * 16 + quad * 4 + reg;
                if (node < N_NODES) {
                    float v = acc[nt][ct][reg];
                    if (col < 80) xlh[(size_t)node * PHL + col] = __float2half_rn(v);
                    else          xr[(size_t)node * HC + (col - 80)] = v;
                }
            }
        }
    }
}

// ---------------------------------------------------------------------------
// Fused build+gemm0 kernel: blocks [0,NCHUNK) run the per-chunk bucket
// histogram; blocks [NCHUNK, NCHUNK+GEMM_TILES) run layer-0 GEMM tiles
// (independent work: reads x_in + wt only). Shared LDS overlaid.
__global__ __launch_bounds__(256) void hist_gemm0_kernel(
        const void* ei, int* __restrict__ hist, int* __restrict__ bcount,
        const float* __restrict__ x_in, const __half* __restrict__ wt0,
        __half* __restrict__ xlh, float* __restrict__ xr) {
    __shared__ __align__(16) char smem[23056];   // max(hist 12.5KB, gemm 23KB)
    __shared__ int s_is64;
    int blk = blockIdx.x;
    int tid = threadIdx.x;
    if (blk >= NCHUNK) {
        __half* xs = (__half*)smem;                       // 128*40*2 = 10240 B
        __half* ws = (__half*)(smem + 10240);             // 160*40*2 = 12800 B
        gemm_tile_body(blk - NCHUNK, x_in, 0, 4, wt0, xlh, xr, xs, ws);
        return;
    }
    int* h = (int*)smem;                                  // NBUCK ints = 12.5 KB
    for (int i = tid; i < NBUCK; i += 256) h[i] = 0;
    detect_is64(ei, tid, &s_is64);
    __syncthreads();
    int is64 = s_is64;
    int e0 = blk * CHUNK, e1 = min(e0 + CHUNK, E_TOT);
    for (int e = e0 + tid; e < e1; e += 4 * 256) {
        int d[4]; int cnt = 0;
        #pragma unroll
        for (int u = 0; u < 4; u++) {
            int ee = e + u * 256;
            if (ee < e1) { d[u] = load_dst(ei, is64, ee); cnt = u + 1; }
        }
        #pragma unroll
        for (int u = 0; u < 4; u++)
            if (u < cnt) atomicAdd(&h[d[u] >> 4], 1);
    }
    __syncthreads();
    for (int i = tid; i < NBUCK; i += 256) {
        int v = h[i];
        int old = v ? atomicAdd(&bcount[i], v) : 0;
        hist[blk * NBUCK + i] = old;
    }
}

// ---------------------------------------------------------------------------
// Single-block exclusive scan over bcount[NBUCK] -> bbase
__global__ void scan_total_kernel(const int* __restrict__ total, int* __restrict__ bbase) {
    __shared__ int wsum[16];
    __shared__ int wpre[16];
    __shared__ int carry;
    int tid = threadIdx.x;
    int lane = tid & 63, w = tid >> 6;
    if (tid == 0) carry = 0;
    __syncthreads();
    for (int base = 0; base < NBUCK; base += 1024) {
        int idx = base + tid;
        int v = (idx < NBUCK) ? total[idx] : 0;
        int sv = v;
        #pragma unroll
        for (int off = 1; off < 64; off <<= 1) {
            int t = __shfl_up(sv, off, 64);
            if (lane >= off) sv += t;
        }
        if (lane == 63) wsum[w] = sv;
        __syncthreads();
        if (w == 0) {
            int s = (lane < 16) ? wsum[lane] : 0;
            #pragma unroll
            for (int off = 1; off < 16; off <<= 1) {
                int t = __shfl_up(s, off, 64);
                if (lane >= off) s += t;
            }
            if (lane < 16) wpre[lane] = s;
        }
        __syncthreads();
        int pre = carry + ((w > 0) ? wpre[w - 1] : 0);
        if (idx < NBUCK) bbase[idx] = pre + sv - v;
        __syncthreads();
        if (tid == 0) carry += wpre[15];
        __syncthreads();
    }
}

// ---------------------------------------------------------------------------
// Phase 3: deterministic-placement scatter into 16-node buckets. LDS cursors only.
__global__ __launch_bounds__(256) void scatter_sort_kernel(
        const void* ei, const int* __restrict__ hist, const int* __restrict__ bbase,
        int* __restrict__ tmp) {
    __shared__ int cur[NBUCK];
    __shared__ int s_is64;
    int tid = threadIdx.x;
    int blk = blockIdx.x;
    for (int i = tid; i < NBUCK; i += 256)
        cur[i] = bbase[i] + hist[blk * NBUCK + i];
    detect_is64(ei, tid, &s_is64);
    __syncthreads();
    int is64 = s_is64;
    int e0 = blk * CHUNK, e1 = min(e0 + CHUNK, E_TOT);
    for (int e = e0 + tid; e < e1; e += 4 * 256) {
        int s[4], d[4]; int cnt = 0;
        #pragma unroll
        for (int u = 0; u < 4; u++) {
            int ee = e + u * 256;
            if (ee < e1) { load_edge(ei, is64, ee, s[u], d[u]); cnt = u + 1; }
        }
        #pragma unroll
        for (int u = 0; u < 4; u++) {
            if (u < cnt) {
                int pos = atomicAdd(&cur[d[u] >> 4], 1);
                tmp[pos] = (s[u] << 4) | (d[u] & 15);
            }
        }
    }
}

// ---------------------------------------------------------------------------
// Phase 4: bucket-grouped tmp -> node-grouped adj + nstart + deg.
// (No deg-histogram fold here — R11 showed 50K direct global atomics into
// ~40 hot bins serialize cross-XCD, +93 us.)
__global__ __launch_bounds__(256) void node_sort_kernel(
        const int* __restrict__ tmp, const int* __restrict__ bbase,
        const int* __restrict__ total,
        int* __restrict__ adj, int* __restrict__ nstart, int* __restrict__ deg) {
    __shared__ int h16[16];
    __shared__ int st16[16];
    __shared__ int cur16[16];
    int tid = threadIdx.x;
    int b = blockIdx.x;
    int base = bbase[b];
    int n = total[b];
    if (tid < 16) h16[tid] = 0;
    __syncthreads();
    for (int k = tid; k < n; k += 256)
        atomicAdd(&h16[tmp[base + k] & 15], 1);
    __syncthreads();
    if (tid == 0) {
        int run = 0;
        #pragma unroll
        for (int c = 0; c < 16; c++) { st16[c] = run; cur16[c] = run; run += h16[c]; }
    }
    __syncthreads();
    for (int k = tid; k < n; k += 256) {
        int p = tmp[base + k];
        int pos = atomicAdd(&cur16[p & 15], 1);
        adj[base + pos] = p >> 4;
    }
    if (tid < 16) {
        nstart[b * 16 + tid] = base + st16[tid];
        deg[b * 16 + tid] = h16[tid];
    }
}

// ---------------------------------------------------------------------------
// Degree permutation, DESCENDING (LPT). Per-block LDS pre-reduction (196
// blocks) keeps global atomics uncontended.
__global__ __launch_bounds__(256) void deghist_kernel(
        const int* __restrict__ deg, int* __restrict__ dh) {
    __shared__ int h[256];
    h[threadIdx.x] = 0;
    __syncthreads();
    int i = blockIdx.x * 256 + threadIdx.x;
    if (i < N_NODES) atomicAdd(&h[min(deg[i], 255)], 1);
    __syncthreads();
    if (h[threadIdx.x]) atomicAdd(&dh[threadIdx.x], h[threadIdx.x]);
}

// degscatter with INLINE descending exclusive scan of dh (degscan kernel
// folded in: each block re-derives the 256-bin scan in LDS, reservations go
// through a zeroed global counter array resv).
__global__ __launch_bounds__(256) void degscatter_kernel(
        const int* __restrict__ deg, const int* __restrict__ dh,
        int* __restrict__ resv, int* __restrict__ perm) {
    __shared__ int sbase[256];
    __shared__ int s[256];
    __shared__ int h[256];
    __shared__ int res[256];
    __shared__ int lc[256];
    int tid = threadIdx.x;
    int idx = 255 - tid;              // descending degree order
    int own = dh[idx];
    s[tid] = own;
    h[tid] = 0; lc[tid] = 0;
    __syncthreads();
    for (int off = 1; off < 256; off <<= 1) {
        int t = (tid >= off) ? s[tid - off] : 0;
        __syncthreads();
        s[tid] += t;
        __syncthreads();
    }
    sbase[idx] = s[tid] - own;        // exclusive, deg 255 first
    __syncthreads();
    int i = blockIdx.x * 256 + tid;
    int d = (i < N_NODES) ? min(deg[i], 255) : -1;
    if (d >= 0) atomicAdd(&h[d], 1);
    __syncthreads();
    res[tid] = h[tid] ? atomicAdd(&resv[tid], h[tid]) : 0;
    __syncthreads();
    if (d >= 0) {
        int off = atomicAdd(&lc[d], 1);
        perm[sbase[d] + res[d] + off] = i;
    }
}

// ---------------------------------------------------------------------------
__global__ __launch_bounds__(256) void gemm_mfma_kernel(
        const void* __restrict__ xin, int in_fp16, int nkt,
        const __half* __restrict__ wt,
        __half* __restrict__ xlh, float* __restrict__ xr) {
    __shared__ __half xs[128 * XS_STRIDE];
    __shared__ __half ws[160 * WS_STRIDE];
    gemm_tile_body(blockIdx.x, xin, in_fp16, nkt, wt, xlh, xr, xs, ws);
}

// ---------------------------------------------------------------------------
// Online-softmax aggregation. Block = 16 nodes (LPT order) x 8 heads x 2
// contiguous splits; batch-8 + batch-4 gathers; packed-fp16 score and
// accumulator. DENSE xl rows: head chunk = 5 dwords at node*80 + h*10 halfs.
__global__ __launch_bounds__(256, 4) void agg_kernel(
        const __half* __restrict__ xlh, const float* __restrict__ xr,
        const float* __restrict__ att, const float* __restrict__ bias,
        const int* __restrict__ nstart, const int* __restrict__ deg,
        const int* __restrict__ adj, const int* __restrict__ perm,
        __half* __restrict__ ybuf, float* __restrict__ yout) {
    int tid = threadIdx.x;
    int b = blockIdx.x;
    int h = tid & 7;
    int split = (tid >> 3) & 1;
    int i_local = tid >> 4;
    int node = perm[b * 16 + i_local];

    int s0 = nstart[node];
    int dg = deg[node];
    int cnt0 = (dg + 1) >> 1;
    int cnt = split ? (dg - cnt0) : cnt0;
    int k0 = s0 + split * cnt0;

#if USE_PK
    h2 xrh[5], atth[5];
    #pragma unroll
    for (int p = 0; p < 5; p++) {
        xrh[p] = (h2){(_Float16)xr[(size_t)node * HC + h * CHANS + 2 * p],
                      (_Float16)xr[(size_t)node * HC + h * CHANS + 2 * p + 1]};
        atth[p] = (h2){(_Float16)att[h * CHANS + 2 * p],
                       (_Float16)att[h * CHANS + 2 * p + 1]};
    }
    const h2 k02 = {(_Float16)NEG_SLOPE, (_Float16)NEG_SLOPE};
    auto score_pk = [&](const unsigned int* wv) {
        float s = 0.f;
        #pragma unroll
        for (int p = 0; p < 5; p++) {
            h2 v = __builtin_bit_cast(h2, wv[p]);
            h2 t = v + xrh[p];
            h2 tl = __builtin_elementwise_max(t, t * k02);
            s = __builtin_amdgcn_fdot2(tl, atth[p], s, false);
        }
        return s;
    };

    float m = -1e30f, l = 0.f;
    h2 acc[5];
    #pragma unroll
    for (int p = 0; p < 5; p++) acc[p] = (h2){(_Float16)0.f, (_Float16)0.f};

    int kk = 0;
    for (; kk + 8 <= cnt; kk += 8) {
        unsigned int w[8][5];
        #pragma unroll
        for (int r = 0; r < 8; r++) {
            int j = adj[k0 + kk + r];
            const unsigned int* p = (const unsigned int*)(xlh + (size_t)j * PHL + h * CHANS);
            #pragma unroll
            for (int q = 0; q < 5; q++) w[r][q] = p[q];
        }
        float sc[8];
        #pragma unroll
        for (int r = 0; r < 8; r++) sc[r] = score_pk(w[r]);
        float mb = m;
        #pragma unroll
        for (int r = 0; r < 8; r++) mb = fmaxf(mb, sc[r]);
        float scale = __expf(m - mb);
        float ps = 0.f;
        #pragma unroll
        for (int r = 0; r < 8; r++) { sc[r] = __expf(sc[r] - mb); ps += sc[r]; }
        l = l * scale + ps;
        _Float16 sch = (_Float16)scale;
        h2 sch2 = (h2){sch, sch};
        #pragma unroll
        for (int p = 0; p < 5; p++) acc[p] *= sch2;
        #pragma unroll
        for (int r = 0; r < 8; r++) {
            _Float16 pr = (_Float16)sc[r];
            h2 pr2 = (h2){pr, pr};
            #pragma unroll
            for (int p = 0; p < 5; p++)
                acc[p] += pr2 * __builtin_bit_cast(h2, w[r][p]);
        }
        m = mb;
    }
    for (; kk + 4 <= cnt; kk += 4) {
        unsigned int w[4][5];
        #pragma unroll
        for (int r = 0; r < 4; r++) {
            int j = adj[k0 + kk + r];
            const unsigned int* p = (const unsigned int*)(xlh + (size_t)j * PHL + h * CHANS);
            #pragma unroll
            for (int q = 0; q < 5; q++) w[r][q] = p[q];
        }
        float sc[4];
        #pragma unroll
        for (int r = 0; r < 4; r++) sc[r] = score_pk(w[r]);
        float mb = m;
        #pragma unroll
        for (int r = 0; r < 4; r++) mb = fmaxf(mb, sc[r]);
        float scale = __expf(m - mb);
        float ps = 0.f;
        #pragma unroll
        for (int r = 0; r < 4; r++) { sc[r] = __expf(sc[r] - mb); ps += sc[r]; }
        l = l * scale + ps;
        _Float16 sch = (_Float16)scale;
        h2 sch2 = (h2){sch, sch};
        #pragma unroll
        for (int p = 0; p < 5; p++) acc[p] *= sch2;
        #pragma unroll
        for (int r = 0; r < 4; r++) {
            _Float16 pr = (_Float16)sc[r];
            h2 pr2 = (h2){pr, pr};
            #pragma unroll
            for (int p = 0; p < 5; p++)
                acc[p] += pr2 * __builtin_bit_cast(h2, w[r][p]);
        }
        m = mb;
    }
    for (; kk < cnt; kk++) {
        int j = adj[k0 + kk];
        const unsigned int* p = (const unsigned int*)(xlh + (size_t)j * PHL + h * CHANS);
        unsigned int w[5] = {p[0], p[1], p[2], p[3], p[4]};
        float s = score_pk(w);
        float mn = fmaxf(m, s);
        float scale = __expf(m - mn);
        float pp = __expf(s - mn);
        l = l * scale + pp;
        _Float16 sch = (_Float16)scale, prh = (_Float16)pp;
        h2 sch2 = (h2){sch, sch}, pr2 = (h2){prh, prh};
        #pragma unroll
        for (int p5 = 0; p5 < 5; p5++)
            acc[p5] = acc[p5] * sch2 + pr2 * __builtin_bit_cast(h2, w[p5]);
        m = mn;
    }

    // merge the two splits (partner 8 lanes away, same wave)
    float accm[CHANS];
    float lt;
    {
        float m2 = __shfl_xor(m, 8, 64);
        float l2 = __shfl_xor(l, 8, 64);
        float mn = fmaxf(m, m2);
        float sc1 = __expf(m - mn), sc2 = __expf(m2 - mn);
        lt = l * sc1 + l2 * sc2;
        #pragma unroll
        for (int p = 0; p < 5; p++) {
            unsigned int ua = __builtin_bit_cast(unsigned int, acc[p]);
            unsigned int ub = (unsigned int)__shfl_xor((int)ua, 8, 64);
            h2 va = __builtin_bit_cast(h2, ua);
            h2 vb = __builtin_bit_cast(h2, ub);
            accm[2 * p]     = (float)va[0] * sc1 + (float)vb[0] * sc2;
            accm[2 * p + 1] = (float)va[1] * sc1 + (float)vb[1] * sc2;
        }
    }
#else
    float xr_c[CHANS], att_c[CHANS];
    #pragma unroll
    for (int c = 0; c < CHANS; c++) {
        xr_c[c]  = xr[(size_t)node * HC + h * CHANS + c];
        att_c[c] = att[h * CHANS + c];
    }
    float m = -1e30f, l = 0.f;
    float acc[CHANS];
    #pragma unroll
    for (int c = 0; c < CHANS; c++) acc[c] = 0.f;
    for (int kk = 0; kk < cnt; kk++) {
        int j = adj[k0 + kk];
        const __half* p = xlh + (size_t)j * PHL + h * CHANS;
        float v[CHANS];
        #pragma unroll
        for (int c = 0; c < CHANS; c++) v[c] = __half2float(p[c]);
        float s = 0.f;
        #pragma unroll
        for (int c = 0; c < CHANS; c++) {
            float t = v[c] + xr_c[c];
            t = (t > 0.f) ? t : NEG_SLOPE * t;
            s += att_c[c] * t;
        }
        float mn = fmaxf(m, s);
        float scale = __expf(m - mn);
        float pp = __expf(s - mn);
        l = l * scale + pp;
        #pragma unroll
        for (int c = 0; c < CHANS; c++) acc[c] = acc[c] * scale + pp * v[c];
        m = mn;
    }
    float accm[CHANS];
    float lt;
    {
        float m2 = __shfl_xor(m, 8, 64);
        float l2 = __shfl_xor(l, 8, 64);
        float mn = fmaxf(m, m2);
        float sc1 = __expf(m - mn), sc2 = __expf(m2 - mn);
        lt = l * sc1 + l2 * sc2;
        #pragma unroll
        for (int c = 0; c < CHANS; c++) {
            float a2 = __shfl_xor(acc[c], 8, 64);
            accm[c] = acc[c] * sc1 + a2 * sc2;
        }
    }
#endif

    if (split == 0) {
        float inv = 1.f / (lt + 1e-16f);
        float z[CHANS];
        #pragma unroll
        for (int c = 0; c < CHANS; c++) {
            float t = accm[c] * inv + bias[h * CHANS + c];
            z[c] = (t > 0.f) ? t : (__expf(t) - 1.f);
        }
        if (yout) {
            #pragma unroll
            for (int c = 0; c < CHANS; c++)
                yout[(size_t)node * HC + h * CHANS + c] = z[c];
        } else {
            unsigned int* dst = (unsigned int*)(ybuf + (size_t)node * PHL + h * CHANS);
            #pragma unroll
            for (int p = 0; p < 5; p++) {
                __half2 hp = __halves2half2(__float2half_rn(z[2 * p]),
                                            __float2half_rn(z[2 * p + 1]));
                dst[p] = *(unsigned int*)&hp;
            }
        }
    }
}

// ---------------------------------------------------------------------------
extern "C" void kernel_launch(void* const* d_in, const int* in_sizes, int n_in,
                              void* d_out, int out_size, void* d_ws, size_t ws_size,
                              hipStream_t stream) {
    const float* x_in = (const float*)d_in[0];
    const void*  ei   = d_in[1];
    const float* Wl[3] = {(const float*)d_in[2], (const float*)d_in[6],  (const float*)d_in[10]};
    const float* Wr[3] = {(const float*)d_in[3], (const float*)d_in[7],  (const float*)d_in[11]};
    const float* At[3] = {(const float*)d_in[4], (const float*)d_in[8],  (const float*)d_in[12]};
    const float* Bi[3] = {(const float*)d_in[5], (const float*)d_in[9],  (const float*)d_in[13]};
    float* out = (float*)d_out;

    char* ws = (char*)d_ws;
    size_t off = 0;
    auto alloc = [&](size_t bytes) {
        void* p = ws + off;
        off += (bytes + 255) & ~(size_t)255;
        return p;
    };
    __half* xlh   = (__half*)alloc((size_t)N_NODES * PHL * sizeof(__half));
    float*  xr    = (float*)alloc((size_t)N_NODES * HC * sizeof(float));
    __half* buf16 = (__half*)alloc((size_t)N_NODES * PHL * sizeof(__half));
    __half* wt    = (__half*)alloc((size_t)3 * 160 * 128 * sizeof(__half));
    int*   tmp    = (int*)alloc((size_t)E_TOT * sizeof(int));
    int*   adj    = (int*)alloc((size_t)E_TOT * sizeof(int));
    int*   hist   = (int*)alloc((size_t)NCHUNK * NBUCK * sizeof(int));
    int*   bcount = (int*)alloc((size_t)NBUCK * sizeof(int));   // memset range start
    int*   dh     = (int*)alloc(256 * sizeof(int));
    int*   resv   = (int*)alloc(256 * sizeof(int));             // memset range end
    int*   bbase  = (int*)alloc((size_t)NBUCK * sizeof(int));
    int*   nstart = (int*)alloc((size_t)N_NODES * sizeof(int));
    int*   deg    = (int*)alloc((size_t)N_NODES * sizeof(int));
    int*   perm   = (int*)alloc((size_t)N_NODES * sizeof(int));

    // --- build: wconv, fused hist+gemm0, scan, scatter, node_sort, deg pair ---
    hipMemsetAsync(bcount, 0, (size_t)((char*)resv - (char*)bcount) + 1024, stream);
    wconv_kernel<<<480, 128, 0, stream>>>(Wl[0], Wr[0], Wl[1], Wr[1], Wl[2], Wr[2], wt);
    hist_gemm0_kernel<<<NCHUNK + GEMM_TILES, 256, 0, stream>>>(
        ei, hist, bcount, x_in, wt, xlh, xr);
    scan_total_kernel<<<1, 1024, 0, stream>>>(bcount, bbase);
    scatter_sort_kernel<<<NCHUNK, 256, 0, stream>>>(ei, hist, bbase, tmp);
    node_sort_kernel<<<NBUCK, 256, 0, stream>>>(tmp, bbase, bcount, adj, nstart, deg);
    int nblocks = (N_NODES + 255) / 256;
    deghist_kernel<<<nblocks, 256, 0, stream>>>(deg, dh);
    degscatter_kernel<<<nblocks, 256, 0, stream>>>(deg, dh, resv, perm);

    // --- 3 GATv2 layers (layer-0 gemm already done in hist_gemm0) ---
    const void* cur = (const void*)buf16;
    for (int layer = 0; layer < 3; layer++) {
        if (layer > 0) {
            gemm_mfma_kernel<<<GEMM_TILES, 256, 0, stream>>>(
                cur, 1, 3, wt + (size_t)layer * 160 * 128, xlh, xr);
        }
        __half* ybuf = (layer == 2) ? nullptr : buf16;
        float*  yout = (layer == 2) ? out : nullptr;
        agg_kernel<<<NBUCK, 256, 0, stream>>>(xlh, xr, At[layer], Bi[layer],
                                              nstart, deg, adj, perm, ybuf, yout);
    }
}